// Round 9
// baseline (344.327 us; speedup 1.0000x reference)
//
#include <hip/hip_runtime.h>
#include <hip/hip_bf16.h>

typedef unsigned short u16;
typedef unsigned int u32;
typedef __attribute__((ext_vector_type(8))) short s16x8;
typedef __attribute__((ext_vector_type(4))) float f32x4;

__device__ __forceinline__ u16 f2bf(float f) {
    union { float f; u32 u; } x; x.f = f;
    u32 r = x.u + 0x7fffu + ((x.u >> 16) & 1u);
    return (u16)(r >> 16);
}
// packed-bf16 u32 -> two f32 (lo / hi), 1 VALU op each
__device__ __forceinline__ float bflo(u32 v) {
    union { u32 u; float f; } x; x.u = v << 16; return x.f;
}
__device__ __forceinline__ float bfhi(u32 v) {
    union { u32 u; float f; } x; x.u = v & 0xffff0000u; return x.f;
}
// two f32 -> packed bf16x2 in ONE VALU op (RNE), lo = a, hi = b
__device__ __forceinline__ u32 cvt_pk_bf16(float a, float b) {
    u32 r;
    asm("v_cvt_pk_bf16_f32 %0, %1, %2" : "=v"(r) : "v"(a), "v"(b));
    return r;
}
// async global->LDS, 16B per lane. LDS dest must be wave-uniform base + lane*16
__device__ __forceinline__ void gl2lds(const u16* g, u16* l) {
    __builtin_amdgcn_global_load_lds(
        (const __attribute__((address_space(1))) unsigned int*)g,
        (__attribute__((address_space(3))) unsigned int*)l, 16, 0, 0);
}

#define L_TOK 21952      // 28^3
#define C_DIM 192
#define LOG2E 1.4426950408889634f
#define Q2SCALE 0.2550565444463649f   // (1/sqrt(32)) * log2(e)
#define BT_STR 352       // bias table query-stride (n0+3 <= 351)

// ---------------------------------------------------------------------------
// Convert the 4 weight matrices f32 -> bf16 (contiguous dst buffer).
// ---------------------------------------------------------------------------
__global__ __launch_bounds__(256) void cvt_k(const float* __restrict__ s0, // 110592 qkv_w
                                             const float* __restrict__ s1, // 36864  proj_w
                                             const float* __restrict__ s2, // 147456 fc1_w
                                             const float* __restrict__ s3, // 147456 fc2_w
                                             u16* __restrict__ dst)
{
    int i = blockIdx.x * 256 + threadIdx.x;   // grid covers 442368
    float v;
    if (i < 110592) v = s0[i];
    else if (i < 147456) v = s1[i - 110592];
    else if (i < 294912) v = s2[i - 147456];
    else v = s3[i - 294912];
    dst[i] = f2bf(v);
}

// ---------------------------------------------------------------------------
// Rel-pos bias per (head, window-type), TRANSPOSED (key-major), premultiplied
// by log2(e), structural shift-mask and pad FOLDED IN, stored bf16:
//   biasT[hh*8+wt][key m (352)][query n (352)]  (bf16, 11.9 MB, L3-resident).
// masked (different shift region) -> -100 -> exp2 underflows to 0.
// pad rows/cols (>342)            -> -1e5 -> exp2 == 0 exactly.
// ---------------------------------------------------------------------------
__global__ __launch_bounds__(256) void bias48_k(const float* __restrict__ rpb,
                                                u16* __restrict__ biasT)
{
    const int gid = blockIdx.x * 256 + threadIdx.x;   // < 48*352*88
    const int z = gid / 30976;                        // 352*88
    const int rem = gid - z * 30976;
    const int m = rem / 88;
    const int n0 = (rem - m * 88) * 4;
    const int hh = z >> 3, wt = z & 7;

    u16 v[4];
    if (m <= 342) {
        const int hm = m / 49, r2 = m - hm * 49, wm = r2 / 7, tm = r2 - wm * 7;
        const int rm = ((wt & 4) ? (hm < 4 ? 1 : 2) : 0) * 9
                     + ((wt & 2) ? (wm < 4 ? 1 : 2) : 0) * 3
                     + ((wt & 1) ? (tm < 4 ? 1 : 2) : 0);
        #pragma unroll
        for (int j = 0; j < 4; j++) {
            const int n = n0 + j;
            float b = -100000.0f;
            if (n <= 342) {
                int hq = n / 49, r1 = n - hq * 49, wq = r1 / 7, tq = r1 - wq * 7;
                int idx = ((hq - hm + 6) * 13 + (wq - wm + 6)) * 13 + (tq - tm + 6);
                b = rpb[idx * 6 + hh];
                int rq = ((wt & 4) ? (hq < 4 ? 1 : 2) : 0) * 9
                       + ((wt & 2) ? (wq < 4 ? 1 : 2) : 0) * 3
                       + ((wt & 1) ? (tq < 4 ? 1 : 2) : 0);
                if (rq != rm) b -= 100.0f;
                b *= LOG2E;
            }
            v[j] = f2bf(b);
        }
    } else {
        const u16 neg = f2bf(-100000.0f);
        v[0] = neg; v[1] = neg; v[2] = neg; v[3] = neg;
    }
    u32 lo = (u32)v[0] | ((u32)v[1] << 16);
    u32 hi = (u32)v[2] | ((u32)v[3] << 16);
    *(uint2*)&biasT[((size_t)z * 352 + m) * BT_STR + n0] = (uint2){lo, hi};
}

// ---------------------------------------------------------------------------
// LayerNorm: f32 in, bf16 out. MODE 0 only now: LN + cyclic shift(-3) +
// window partition scatter -> xw (Bn*343, 192).  (LN2 is fused into projln_k.)
// ---------------------------------------------------------------------------
template<int MODE>
__global__ __launch_bounds__(256) void ln_k(const float* __restrict__ in,
                                            const float* __restrict__ g,
                                            const float* __restrict__ b,
                                            u16* __restrict__ out)
{
    const int lane = threadIdx.x & 63, wv = threadIdx.x >> 6;
    const int tok = blockIdx.x * 4 + wv;   // < 43904 always (10976*4)
    size_t base = (size_t)tok * C_DIM;
    float x0 = in[base + lane];
    float x1 = in[base + 64 + lane];
    float x2 = in[base + 128 + lane];
    float s = x0 + x1 + x2;
    float sq = x0 * x0 + x1 * x1 + x2 * x2;
    #pragma unroll
    for (int off = 32; off > 0; off >>= 1) {
        s += __shfl_xor(s, off, 64);
        sq += __shfl_xor(sq, off, 64);
    }
    const float mean = s * (1.0f / 192.0f);
    float var = sq * (1.0f / 192.0f) - mean * mean;
    var = fmaxf(var, 0.0f);
    const float rstd = rsqrtf(var + 1e-5f);

    size_t obase;
    if (MODE == 0) {
        int bi = tok / L_TOK;
        int l = tok - bi * L_TOK;
        int h = l / 784;
        int rm = l - h * 784;
        int w = rm / 28;
        int t = rm - w * 28;
        int hs = h + 25; if (hs >= 28) hs -= 28;
        int ws = w + 25; if (ws >= 28) ws -= 28;
        int ts = t + 25; if (ts >= 28) ts -= 28;
        int win = ((bi * 4 + hs / 7) * 4 + ws / 7) * 4 + ts / 7;
        int n = (hs % 7) * 49 + (ws % 7) * 7 + (ts % 7);
        obase = ((size_t)win * 343 + n) * C_DIM;
    } else {
        obase = base;
    }
    #pragma unroll
    for (int i = 0; i < 3; i++) {
        int c = lane + i * 64;
        float xv = (i == 0) ? x0 : (i == 1) ? x1 : x2;
        float y = (xv - mean) * rstd * g[c] + b[c];
        out[obase + c] = f2bf(y);
    }
}

// ---------------------------------------------------------------------------
// 64x64-tile bf16 MFMA GEMM (qkv / fc1 / fc2): C = A @ W^T + bias.
// <=64-VGPR path: acc 16 VGPR, __launch_bounds__(256,8), LDS 16 KB ->
// 8 blocks/CU, 32 waves/CU. K chunked by 64, single-buffered.
// EPI: 0 = bias, q-cols (gcol<192) pre-scaled by scale*log2e -> bf16 (QKV)
//      1 = bias + exact GELU -> bf16 (fc1)
//      2 = bias + f32 residual -> f32 out (fc2 -> d_out)
// ---------------------------------------------------------------------------
template<int K, int EPI>
__global__ __launch_bounds__(256, 8) void gemm64_k(const u16* __restrict__ A,
                                                   const u16* __restrict__ W,
                                                   const float* __restrict__ bias,
                                                   void* __restrict__ outp,
                                                   const void* __restrict__ resp,
                                                   int Ncols)
{
    __shared__ __align__(16) u16 As[2 * 2048];   // 8 KB: [kt][64 rows][32 k]
    __shared__ __align__(16) u16 Bs[2 * 2048];   // 8 KB
    const int t = threadIdx.x;
    const int bm = blockIdx.y;
    const int n0 = blockIdx.x * 64;
    const int lane = t & 63, wv = t >> 6;
    const int r16 = lane & 15, quad = lane >> 4;
    const int ar = t >> 2, ac = (t & 3) * 8;     // 4 threads/row, 8 u16 each
    const size_t abase = (size_t)bm * 64 * K;

    f32x4 acc[4];
    #pragma unroll
    for (int fn = 0; fn < 4; fn++) acc[fn] = (f32x4){0.f, 0.f, 0.f, 0.f};

    for (int kc = 0; kc < K; kc += 64) {
        if (kc) __syncthreads();   // WAR: prior chunk's ds_reads done
        #pragma unroll
        for (int kt = 0; kt < 2; kt++) {
            gl2lds(&A[abase + (size_t)ar * K + kc + kt * 32 + ac], &As[kt * 2048 + 8 * t]);
            gl2lds(&W[(size_t)(n0 + ar) * K + kc + kt * 32 + ac], &Bs[kt * 2048 + 8 * t]);
        }
        __syncthreads();           // drains the 4 async loads
        #pragma unroll
        for (int kt = 0; kt < 2; kt++) {
            s16x8 af = *(const s16x8*)&As[kt * 2048 + (wv * 16 + r16) * 32 + quad * 8];
            #pragma unroll
            for (int fn = 0; fn < 4; fn++) {
                s16x8 bf = *(const s16x8*)&Bs[kt * 2048 + (fn * 16 + r16) * 32 + quad * 8];
                acc[fn] = __builtin_amdgcn_mfma_f32_16x16x32_bf16(af, bf, acc[fn], 0, 0, 0);
            }
        }
    }

    // ---- epilogue: 4 rows x 4 col-fragments per thread ----
    #pragma unroll
    for (int r = 0; r < 4; r++) {
        const int grow = bm * 64 + wv * 16 + quad * 4 + r;
        size_t rowbase = (size_t)grow * ((EPI == 2) ? C_DIM : Ncols);
        #pragma unroll
        for (int fn = 0; fn < 4; fn++) {
            const int gcol = n0 + fn * 16 + r16;
            float v = acc[fn][r] + bias[gcol];
            if (EPI == 0) {
                if (gcol < 192) v *= Q2SCALE;   // pre-scale q (incl. log2e)
                ((u16*)outp)[rowbase + gcol] = f2bf(v);
            } else if (EPI == 1) {
                v = 0.5f * v * (1.0f + erff(v * 0.70710678118654752f));
                ((u16*)outp)[rowbase + gcol] = f2bf(v);
            } else {
                size_t o = rowbase + gcol;
                ((float*)outp)[o] = v + ((const float*)resp)[o];
            }
        }
    }
}

// ---------------------------------------------------------------------------
// FUSED proj GEMM + window-reverse/unshift + residual + LayerNorm2.
// R9 theory: non-attn time has been ~278 us across four GEMM structures ->
// the pipeline is HBM-traffic-bound, not schedule-bound. This kernel
// eliminates ln2's 33.7 MB x2 re-read + one launch by computing LN in the
// proj epilogue. Tile 64 rows x ALL 192 cols (12 fragments, acc 48 VGPR):
// every channel of a token lives in the block -> row LN via quad-group
// shuffle reduce (16 lanes x 12 frags). Emits x2 (f32, fc2 residual) AND
// h2 (bf16, fc1 input) in token order. LDS 32 KB.
// ---------------------------------------------------------------------------
__global__ __launch_bounds__(256) void projln_k(const u16* __restrict__ A,
                                                const u16* __restrict__ W,
                                                const float* __restrict__ bias,
                                                const float* __restrict__ res,
                                                const float* __restrict__ g2,
                                                const float* __restrict__ b2,
                                                float* __restrict__ x2,
                                                u16* __restrict__ h2)
{
    constexpr int K = 192;
    __shared__ __align__(16) u16 As[2 * 2048];   // 8 KB  [kt][64 rows][32 k]
    __shared__ __align__(16) u16 Bs[2 * 6144];   // 24 KB [kt][192 rows][32 k]
    const int t = threadIdx.x, bm = blockIdx.x;
    const int lane = t & 63, wv = t >> 6;
    const int r16 = lane & 15, quad = lane >> 4;
    const int ar = t >> 2, ac = (t & 3) * 8;
    const size_t abase = (size_t)bm * 64 * K;

    f32x4 acc[12];
    #pragma unroll
    for (int fn = 0; fn < 12; fn++) acc[fn] = (f32x4){0.f, 0.f, 0.f, 0.f};

    for (int kc = 0; kc < K; kc += 64) {
        if (kc) __syncthreads();   // WAR: prior chunk's ds_reads done
        #pragma unroll
        for (int kt = 0; kt < 2; kt++) {
            gl2lds(&A[abase + (size_t)ar * K + kc + kt * 32 + ac], &As[kt * 2048 + 8 * t]);
            #pragma unroll
            for (int bb = 0; bb < 3; bb++)
                gl2lds(&W[(size_t)(bb * 64 + ar) * K + kc + kt * 32 + ac],
                       &Bs[kt * 6144 + bb * 2048 + 8 * t]);
        }
        __syncthreads();           // drains the 8 async loads
        #pragma unroll
        for (int kt = 0; kt < 2; kt++) {
            s16x8 af = *(const s16x8*)&As[kt * 2048 + (wv * 16 + r16) * 32 + quad * 8];
            #pragma unroll
            for (int fn = 0; fn < 12; fn++) {
                s16x8 bf = *(const s16x8*)&Bs[kt * 6144 + (fn * 16 + r16) * 32 + quad * 8];
                acc[fn] = __builtin_amdgcn_mfma_f32_16x16x32_bf16(af, bf, acc[fn], 0, 0, 0);
            }
        }
    }

    // ---- fused epilogue: window-reverse + residual + LN2, per row ----
    #pragma unroll
    for (int r = 0; r < 4; r++) {
        const int grow = bm * 64 + wv * 16 + quad * 4 + r;
        int win = grow / 343, n = grow - win * 343;
        int bi = win >> 6, wi = win & 63;
        int hw = wi >> 4, ww = (wi >> 2) & 3, tw = wi & 3;
        int ph = n / 49, rem = n - ph * 49;
        int pw = rem / 7, pt = rem - pw * 7;
        int h = hw * 7 + ph + 3; if (h >= 28) h -= 28;
        int w = ww * 7 + pw + 3; if (w >= 28) w -= 28;
        int tt = tw * 7 + pt + 3; if (tt >= 28) tt -= 28;
        int l = (h * 28 + w) * 28 + tt;
        size_t rowbase = ((size_t)bi * L_TOK + l) * C_DIM;

        float y[12];
        float s = 0.f, sq = 0.f;
        #pragma unroll
        for (int fn = 0; fn < 12; fn++) {
            const int gcol = fn * 16 + r16;
            float v = acc[fn][r] + bias[gcol] + res[rowbase + gcol];
            y[fn] = v; s += v; sq += v * v;
        }
        // reduce across the 16 lanes of this quad group (they hold the row)
        #pragma unroll
        for (int off = 1; off < 16; off <<= 1) {
            s += __shfl_xor(s, off, 64);
            sq += __shfl_xor(sq, off, 64);
        }
        const float mean = s * (1.0f / 192.0f);
        float var = sq * (1.0f / 192.0f) - mean * mean;
        var = fmaxf(var, 0.0f);
        const float rstd = rsqrtf(var + 1e-5f);
        #pragma unroll
        for (int fn = 0; fn < 12; fn++) {
            const int gcol = fn * 16 + r16;
            x2[rowbase + gcol] = y[fn];
            h2[rowbase + gcol] = f2bf((y[fn] - mean) * rstd * g2[gcol] + b2[gcol]);
        }
    }
}

// ---------------------------------------------------------------------------
// MFMA attention. Block = (head hh, window win), 4 waves (256 thr).
// LDS 50.7 KB -> 3 blocks/CU (grid 768 = 256 CU x 3, full residency).
// FROZEN at R4-verified state (65-74 us band):
//  - folded 48-slab bf16 bias table (mask-free softmax body).
//  - ones-MFMA rowsum + v_cvt_pk_bf16_f32 P-pack.
//  - BOTH lgkmcnt(0) fences in the PV loop are register-pressure dams:
//    removing them spilled sacc to scratch (R3: +200 MB HBM, 76->125 us).
// ---------------------------------------------------------------------------
__global__ __launch_bounds__(256, 3) void attn_k(const u16* __restrict__ qkv,
                                                 const u16* __restrict__ biasAll,
                                                 u16* __restrict__ out)
{
    __shared__ __align__(16) u16 Ks[352 * 32];       // 22528 B
    __shared__ __align__(16) u16 Vt[32 * 360];       // 23040 B
    __shared__ __align__(16) u16 Pb[4][16 * 40];     //  5120 B

    const int hh = blockIdx.x;   // head 0..5
    const int win = blockIdx.y;  // 0..127
    const int wi = win & 63;
    const int t = threadIdx.x, lane = t & 63, wv = t >> 6;
    const int r16 = lane & 15, quad = lane >> 4;
    const size_t qbase = (size_t)win * 343 * 576 + hh * 32;

    // ---- stage K rows (343 x 32), zero pad rows 343..351 ----
    for (int j = t; j < 343 * 4; j += 256) {
        int m = j >> 2, ch = j & 3;
        *(uint4*)&Ks[m * 32 + ch * 8] = *(const uint4*)&qkv[qbase + (size_t)m * 576 + 192 + ch * 8];
    }
    if (t < 36) {
        int m = 343 + (t >> 2), ch = t & 3;
        *(uint4*)&Ks[m * 32 + ch * 8] = (uint4){0u, 0u, 0u, 0u};
    }
    // ---- stage V transposed + column-permuted: Vt[d][phys(m)] ----
    for (int i = t; i < 343 * 16; i += 256) {
        int m = i >> 4, d2 = (i & 15) * 2;
        int pm = (m & ~31) + 2 * (m & 15) + ((m >> 4) & 1);
        u32 w2 = *(const u32*)&qkv[qbase + (size_t)m * 576 + 384 + d2];
        Vt[d2 * 360 + pm] = (u16)(w2 & 0xffffu);
        Vt[(d2 + 1) * 360 + pm] = (u16)(w2 >> 16);
    }
    // zero pads (logical m 343..351 at their permuted slots), all 32 d rows
    for (int i = t; i < 32 * 9; i += 256) {
        int d = i / 9, m = 343 + i % 9;
        int pm = (m & ~31) + 2 * (m & 15) + ((m >> 4) & 1);
        Vt[d * 360 + pm] = 0;
    }
    __syncthreads();

    // window type -> pre-folded bias+mask slab
    const int wt = (((wi >> 4) == 3) ? 4 : 0) | ((((wi >> 2) & 3) == 3) ? 2 : 0)
                 | (((wi & 3) == 3) ? 1 : 0);
    const u16* biashT = biasAll + (size_t)(hh * 8 + wt) * 352 * BT_STR;

    // ones B-fragment (bf16 1.0 everywhere) for the rowsum MFMA
    s16x8 onesb;
    #pragma unroll
    for (int j = 0; j < 8; j++) onesb[j] = (short)0x3f80;

    for (int qt = 0; qt < 6; qt++) {
        const int row0 = qt * 64 + wv * 16;          // wave's 16 rows
        if (row0 > 342) continue;                    // wave-uniform early out
        // ---- Q A-fragment (row = r16, k = quad*8+j), clamped rows ----
        int qrow = row0 + r16; if (qrow > 342) qrow = 342;
        s16x8 qa = *(const s16x8*)&qkv[qbase + (size_t)qrow * 576 + quad * 8];

        const int n0 = row0 + quad * 4;

        // ---- S = Q K^T, acc init from folded bf16 bias+mask (uint2) ----
        f32x4 sacc[22];
        #pragma unroll
        for (int fn = 0; fn < 22; fn++) {
            const int col = fn * 16 + r16;           // key idx, pads included
            uint2 bv = *(const uint2*)&biashT[(size_t)col * BT_STR + n0];
            sacc[fn][0] = bflo(bv.x);
            sacc[fn][1] = bfhi(bv.x);
            sacc[fn][2] = bflo(bv.y);
            sacc[fn][3] = bfhi(bv.y);
        }
        #pragma unroll
        for (int fn = 0; fn < 22; fn++) {
            s16x8 kb = *(const s16x8*)&Ks[(fn * 16 + r16) * 32 + quad * 8];
            sacc[fn] = __builtin_amdgcn_mfma_f32_16x16x32_bf16(qa, kb, sacc[fn], 0, 0, 0);
        }

        // ---- softmax: p = exp2(s); mask/pad already -inf-folded -> 0 ----
        #pragma unroll
        for (int fn = 0; fn < 22; fn++) {
            #pragma unroll
            for (int r = 0; r < 4; r++)
                sacc[fn][r] = exp2f(fminf(sacc[fn][r], 42.0f));
        }

        // ---- PV in 32-col chunks: packed C->LDS->A round-trip + MFMA ----
        // osum accumulates P @ ones == rowsum (row layout matches n0+r).
        u16* pw = &Pb[wv][0];
        u32* pw32 = (u32*)pw;
        f32x4 oacc0 = (f32x4){0.f, 0.f, 0.f, 0.f};
        f32x4 oacc1 = (f32x4){0.f, 0.f, 0.f, 0.f};
        f32x4 osum  = (f32x4){0.f, 0.f, 0.f, 0.f};
        #pragma unroll
        for (int c = 0; c < 11; c++) {
            // WAR fence: prior chunk's reads complete before overwrite
            // (also a register-pressure dam -- see kernel comment)
            asm volatile("s_waitcnt lgkmcnt(0)" ::: "memory");
            #pragma unroll
            for (int r = 0; r < 4; r++)
                pw32[(quad * 4 + r) * 20 + r16] = cvt_pk_bf16(sacc[2 * c][r], sacc[2 * c + 1][r]);
            // RAW fence: writes committed before reads issue
            asm volatile("s_waitcnt lgkmcnt(0)" ::: "memory");
            s16x8 pa = *(const s16x8*)&pw[r16 * 40 + quad * 8];
            s16x8 vb0 = *(const s16x8*)&Vt[r16 * 360 + c * 32 + quad * 8];
            s16x8 vb1 = *(const s16x8*)&Vt[(16 + r16) * 360 + c * 32 + quad * 8];
            oacc0 = __builtin_amdgcn_mfma_f32_16x16x32_bf16(pa, vb0, oacc0, 0, 0, 0);
            oacc1 = __builtin_amdgcn_mfma_f32_16x16x32_bf16(pa, vb1, oacc1, 0, 0, 0);
            osum  = __builtin_amdgcn_mfma_f32_16x16x32_bf16(pa, onesb, osum, 0, 0, 0);
        }

        // ---- epilogue: fold 1/rowsum, store bf16 ----
        #pragma unroll
        for (int r = 0; r < 4; r++) {
            const int n = n0 + r;
            if (n < 343) {
                const float rs = osum[r];
                const float inv = rs > 0.0f ? 1.0f / rs : 0.0f;
                size_t o = ((size_t)win * 343 + n) * C_DIM + hh * 32;
                out[o + r16] = f2bf(oacc0[r] * inv);
                out[o + 16 + r16] = f2bf(oacc1[r] * inv);
            }
        }
    }
}

// ---------------------------------------------------------------------------
extern "C" void kernel_launch(void* const* d_in, const int* in_sizes, int n_in,
                              void* d_out, int out_size, void* d_ws, size_t ws_size,
                              hipStream_t stream)
{
    const float* x      = (const float*)d_in[0];
    const float* g1     = (const float*)d_in[2];
    const float* b1     = (const float*)d_in[3];
    const float* qkv_w  = (const float*)d_in[4];
    const float* qkv_b  = (const float*)d_in[5];
    const float* rpb    = (const float*)d_in[6];
    const float* proj_w = (const float*)d_in[7];
    const float* proj_b = (const float*)d_in[8];
    const float* g2     = (const float*)d_in[9];
    const float* b2     = (const float*)d_in[10];
    const float* fc1_w  = (const float*)d_in[11];
    const float* fc1_b  = (const float*)d_in[12];
    const float* fc2_w  = (const float*)d_in[13];
    const float* fc2_b  = (const float*)d_in[14];

    // workspace layout (bytes). Region lifetimes (stream-ordered):
    //   [0, 16.9M):    xw (ln1->qkv) -> biasT (bias48->attn) -> h2 (projln->fc1)
    //   [16.9M, 67.4M): qkv (qkv->attn) }  a1 (fc1->fc2) overlays
    //   [67.4M, 84.3M): attn_out (attn->projln) }  both, dead by fc1
    //   [84.3M, 118M):  x2 f32 (projln->fc2 residual)
    //   [118M, ...):    wbf weight cache
    char* ws = (char*)d_ws;
    u16* xw        = (u16*)(ws + 0);                 // 16,861,184 B
    u16* biasT     = (u16*)(ws + 0);                 // 11,894,784 B (after QKV gemm)
    u16* h2        = (u16*)(ws + 0);                 // 16,861,184 B (after attn)
    u16* qkv       = (u16*)(ws + 16861184);          // 50,583,552 B
    u16* a1        = (u16*)(ws + 16861184);          // 67,444,736 B (after projln)
    u16* attn_out  = (u16*)(ws + 67444736);          // 16,861,184 B
    float* x2      = (float*)(ws + 84305920);        // 33,722,368 B
    u16* wbf       = (u16*)(ws + 118028288);         //    884,736 B  (~113 MB total)
    u16* qkv_wb = wbf;
    u16* proj_wb = wbf + 110592;
    u16* fc1_wb = wbf + 147456;
    u16* fc2_wb = wbf + 294912;

    cvt_k<<<dim3(1728), 256, 0, stream>>>(qkv_w, proj_w, fc1_w, fc2_w, wbf);
    ln_k<0><<<dim3(10976), 256, 0, stream>>>(x, g1, b1, xw);
    gemm64_k<192, 0><<<dim3(9, 686), 256, 0, stream>>>(xw, qkv_wb, qkv_b, qkv, nullptr, 576);
    bias48_k<<<dim3(5808), 256, 0, stream>>>(rpb, biasT);
    attn_k<<<dim3(6, 128), 256, 0, stream>>>(qkv, biasT, attn_out);
    projln_k<<<dim3(686), 256, 0, stream>>>(attn_out, proj_wb, proj_b, x, g2, b2, x2, h2);
    gemm64_k<192, 1><<<dim3(12, 686), 256, 0, stream>>>(h2, fc1_wb, fc1_b, a1, nullptr, 768);
    gemm64_k<768, 2><<<dim3(3, 686), 256, 0, stream>>>(a1, fc2_wb, fc2_b, d_out, x2, 192);
}

// Round 10
// 321.542 us; speedup vs baseline: 1.0709x; 1.0709x over previous
//
#include <hip/hip_runtime.h>
#include <hip/hip_bf16.h>

typedef unsigned short u16;
typedef unsigned int u32;
typedef __attribute__((ext_vector_type(8))) short s16x8;
typedef __attribute__((ext_vector_type(4))) float f32x4;

__device__ __forceinline__ u16 f2bf(float f) {
    union { float f; u32 u; } x; x.f = f;
    u32 r = x.u + 0x7fffu + ((x.u >> 16) & 1u);
    return (u16)(r >> 16);
}
// packed-bf16 u32 -> two f32 (lo / hi), 1 VALU op each
__device__ __forceinline__ float bflo(u32 v) {
    union { u32 u; float f; } x; x.u = v << 16; return x.f;
}
__device__ __forceinline__ float bfhi(u32 v) {
    union { u32 u; float f; } x; x.u = v & 0xffff0000u; return x.f;
}
// two f32 -> packed bf16x2 in ONE VALU op (RNE), lo = a, hi = b
__device__ __forceinline__ u32 cvt_pk_bf16(float a, float b) {
    u32 r;
    asm("v_cvt_pk_bf16_f32 %0, %1, %2" : "=v"(r) : "v"(a), "v"(b));
    return r;
}
// async global->LDS, 16B per lane. LDS dest must be wave-uniform base + lane*16
__device__ __forceinline__ void gl2lds(const u16* g, u16* l) {
    __builtin_amdgcn_global_load_lds(
        (const __attribute__((address_space(1))) unsigned int*)g,
        (__attribute__((address_space(3))) unsigned int*)l, 16, 0, 0);
}

#define L_TOK 21952      // 28^3
#define C_DIM 192
#define LOG2E 1.4426950408889634f
#define Q2SCALE 0.2550565444463649f   // (1/sqrt(32)) * log2(e)
#define BT_STR 352       // bias table query-stride (n0+3 <= 351)

// ---------------------------------------------------------------------------
// Convert the 4 weight matrices f32 -> bf16 (contiguous dst buffer).
// ---------------------------------------------------------------------------
__global__ __launch_bounds__(256) void cvt_k(const float* __restrict__ s0, // 110592 qkv_w
                                             const float* __restrict__ s1, // 36864  proj_w
                                             const float* __restrict__ s2, // 147456 fc1_w
                                             const float* __restrict__ s3, // 147456 fc2_w
                                             u16* __restrict__ dst)
{
    int i = blockIdx.x * 256 + threadIdx.x;   // grid covers 442368
    float v;
    if (i < 110592) v = s0[i];
    else if (i < 147456) v = s1[i - 110592];
    else if (i < 294912) v = s2[i - 147456];
    else v = s3[i - 294912];
    dst[i] = f2bf(v);
}

// ---------------------------------------------------------------------------
// Rel-pos bias per (head, window-type), TRANSPOSED (key-major), premultiplied
// by log2(e), structural shift-mask and pad FOLDED IN, stored bf16:
//   biasT[hh*8+wt][key m (352)][query n (352)]  (bf16, 11.9 MB, L3-resident).
// masked (different shift region) -> -100 -> exp2 underflows to 0.
// pad rows/cols (>342)            -> -1e5 -> exp2 == 0 exactly.
// ---------------------------------------------------------------------------
__global__ __launch_bounds__(256) void bias48_k(const float* __restrict__ rpb,
                                                u16* __restrict__ biasT)
{
    const int gid = blockIdx.x * 256 + threadIdx.x;   // < 48*352*88
    const int z = gid / 30976;                        // 352*88
    const int rem = gid - z * 30976;
    const int m = rem / 88;
    const int n0 = (rem - m * 88) * 4;
    const int hh = z >> 3, wt = z & 7;

    u16 v[4];
    if (m <= 342) {
        const int hm = m / 49, r2 = m - hm * 49, wm = r2 / 7, tm = r2 - wm * 7;
        const int rm = ((wt & 4) ? (hm < 4 ? 1 : 2) : 0) * 9
                     + ((wt & 2) ? (wm < 4 ? 1 : 2) : 0) * 3
                     + ((wt & 1) ? (tm < 4 ? 1 : 2) : 0);
        #pragma unroll
        for (int j = 0; j < 4; j++) {
            const int n = n0 + j;
            float b = -100000.0f;
            if (n <= 342) {
                int hq = n / 49, r1 = n - hq * 49, wq = r1 / 7, tq = r1 - wq * 7;
                int idx = ((hq - hm + 6) * 13 + (wq - wm + 6)) * 13 + (tq - tm + 6);
                b = rpb[idx * 6 + hh];
                int rq = ((wt & 4) ? (hq < 4 ? 1 : 2) : 0) * 9
                       + ((wt & 2) ? (wq < 4 ? 1 : 2) : 0) * 3
                       + ((wt & 1) ? (tq < 4 ? 1 : 2) : 0);
                if (rq != rm) b -= 100.0f;
                b *= LOG2E;
            }
            v[j] = f2bf(b);
        }
    } else {
        const u16 neg = f2bf(-100000.0f);
        v[0] = neg; v[1] = neg; v[2] = neg; v[3] = neg;
    }
    u32 lo = (u32)v[0] | ((u32)v[1] << 16);
    u32 hi = (u32)v[2] | ((u32)v[3] << 16);
    *(uint2*)&biasT[((size_t)z * 352 + m) * BT_STR + n0] = (uint2){lo, hi};
}

// ---------------------------------------------------------------------------
// LayerNorm: f32 in, bf16 out. MODE 0 only now: LN + cyclic shift(-3) +
// window partition scatter -> xw (Bn*343, 192).  (LN2 is fused into projln_k.)
// ---------------------------------------------------------------------------
template<int MODE>
__global__ __launch_bounds__(256) void ln_k(const float* __restrict__ in,
                                            const float* __restrict__ g,
                                            const float* __restrict__ b,
                                            u16* __restrict__ out)
{
    const int lane = threadIdx.x & 63, wv = threadIdx.x >> 6;
    const int tok = blockIdx.x * 4 + wv;   // < 43904 always (10976*4)
    size_t base = (size_t)tok * C_DIM;
    float x0 = in[base + lane];
    float x1 = in[base + 64 + lane];
    float x2 = in[base + 128 + lane];
    float s = x0 + x1 + x2;
    float sq = x0 * x0 + x1 * x1 + x2 * x2;
    #pragma unroll
    for (int off = 32; off > 0; off >>= 1) {
        s += __shfl_xor(s, off, 64);
        sq += __shfl_xor(sq, off, 64);
    }
    const float mean = s * (1.0f / 192.0f);
    float var = sq * (1.0f / 192.0f) - mean * mean;
    var = fmaxf(var, 0.0f);
    const float rstd = rsqrtf(var + 1e-5f);

    size_t obase;
    if (MODE == 0) {
        int bi = tok / L_TOK;
        int l = tok - bi * L_TOK;
        int h = l / 784;
        int rm = l - h * 784;
        int w = rm / 28;
        int t = rm - w * 28;
        int hs = h + 25; if (hs >= 28) hs -= 28;
        int ws = w + 25; if (ws >= 28) ws -= 28;
        int ts = t + 25; if (ts >= 28) ts -= 28;
        int win = ((bi * 4 + hs / 7) * 4 + ws / 7) * 4 + ts / 7;
        int n = (hs % 7) * 49 + (ws % 7) * 7 + (ts % 7);
        obase = ((size_t)win * 343 + n) * C_DIM;
    } else {
        obase = base;
    }
    #pragma unroll
    for (int i = 0; i < 3; i++) {
        int c = lane + i * 64;
        float xv = (i == 0) ? x0 : (i == 1) ? x1 : x2;
        float y = (xv - mean) * rstd * g[c] + b[c];
        out[obase + c] = f2bf(y);
    }
}

// ---------------------------------------------------------------------------
// 64x64-tile bf16 MFMA GEMM (qkv / fc1 / fc2): C = A @ W^T + bias.
// <=64-VGPR path: acc 16 VGPR, __launch_bounds__(256,8), LDS 16 KB ->
// 8 blocks/CU, 32 waves/CU. K chunked by 64, single-buffered.
// R10: 1D grid + bijective XCD-chunk swizzle (T1, m204 formula). Consecutive
// logical tiles share an A-strip (n-index fastest); chunking puts them on
// ONE XCD so the 9x (qkv) / 12x (fc1) / 3x (fc2) A re-reads become 4MB-L2
// hits instead of cross-die L3/HBM fetches (~390 MB eliminated).
// EPI: 0 = bias, q-cols (gcol<192) pre-scaled by scale*log2e -> bf16 (QKV)
//      1 = bias + exact GELU -> bf16 (fc1)
//      2 = bias + f32 residual -> f32 out (fc2 -> d_out)
// ---------------------------------------------------------------------------
template<int K, int EPI, int NX>
__global__ __launch_bounds__(256, 8) void gemm64_k(const u16* __restrict__ A,
                                                   const u16* __restrict__ W,
                                                   const float* __restrict__ bias,
                                                   void* __restrict__ outp,
                                                   const void* __restrict__ resp,
                                                   int Ncols)
{
    __shared__ __align__(16) u16 As[2 * 2048];   // 8 KB: [kt][64 rows][32 k]
    __shared__ __align__(16) u16 Bs[2 * 2048];   // 8 KB
    const int t = threadIdx.x;
    // --- bijective XCD-chunk swizzle (HW round-robins orig%8 -> XCD) ---
    constexpr int NWG = NX * 686;
    constexpr int QQ = NWG >> 3, RR = NWG & 7;
    const int orig = blockIdx.x;
    const int xcd = orig & 7, rnk = orig >> 3;
    const int wgid = (xcd < RR ? xcd * (QQ + 1) : RR * (QQ + 1) + (xcd - RR) * QQ) + rnk;
    const int bm = wgid / NX;
    const int n0 = (wgid - bm * NX) * 64;

    const int lane = t & 63, wv = t >> 6;
    const int r16 = lane & 15, quad = lane >> 4;
    const int ar = t >> 2, ac = (t & 3) * 8;     // 4 threads/row, 8 u16 each
    const size_t abase = (size_t)bm * 64 * K;

    f32x4 acc[4];
    #pragma unroll
    for (int fn = 0; fn < 4; fn++) acc[fn] = (f32x4){0.f, 0.f, 0.f, 0.f};

    for (int kc = 0; kc < K; kc += 64) {
        if (kc) __syncthreads();   // WAR: prior chunk's ds_reads done
        #pragma unroll
        for (int kt = 0; kt < 2; kt++) {
            gl2lds(&A[abase + (size_t)ar * K + kc + kt * 32 + ac], &As[kt * 2048 + 8 * t]);
            gl2lds(&W[(size_t)(n0 + ar) * K + kc + kt * 32 + ac], &Bs[kt * 2048 + 8 * t]);
        }
        __syncthreads();           // drains the 4 async loads
        #pragma unroll
        for (int kt = 0; kt < 2; kt++) {
            s16x8 af = *(const s16x8*)&As[kt * 2048 + (wv * 16 + r16) * 32 + quad * 8];
            #pragma unroll
            for (int fn = 0; fn < 4; fn++) {
                s16x8 bf = *(const s16x8*)&Bs[kt * 2048 + (fn * 16 + r16) * 32 + quad * 8];
                acc[fn] = __builtin_amdgcn_mfma_f32_16x16x32_bf16(af, bf, acc[fn], 0, 0, 0);
            }
        }
    }

    // ---- epilogue: 4 rows x 4 col-fragments per thread ----
    #pragma unroll
    for (int r = 0; r < 4; r++) {
        const int grow = bm * 64 + wv * 16 + quad * 4 + r;
        size_t rowbase = (size_t)grow * ((EPI == 2) ? C_DIM : Ncols);
        #pragma unroll
        for (int fn = 0; fn < 4; fn++) {
            const int gcol = n0 + fn * 16 + r16;
            float v = acc[fn][r] + bias[gcol];
            if (EPI == 0) {
                if (gcol < 192) v *= Q2SCALE;   // pre-scale q (incl. log2e)
                ((u16*)outp)[rowbase + gcol] = f2bf(v);
            } else if (EPI == 1) {
                v = 0.5f * v * (1.0f + erff(v * 0.70710678118654752f));
                ((u16*)outp)[rowbase + gcol] = f2bf(v);
            } else {
                size_t o = rowbase + gcol;
                ((float*)outp)[o] = v + ((const float*)resp)[o];
            }
        }
    }
}

// ---------------------------------------------------------------------------
// FUSED proj GEMM + window-reverse/unshift + residual + LayerNorm2.
// Eliminates ln2's 33.7 MB x2 re-read + one launch (R9, ~8 us on the
// non-attn path). Tile 64 rows x ALL 192 cols (12 fragments, acc 48 VGPR);
// row LN via quad-group shuffle reduce. Emits x2 (f32) and h2 (bf16).
// No XCD swizzle: blocks share no A operand (W is L2-resident everywhere).
// ---------------------------------------------------------------------------
__global__ __launch_bounds__(256) void projln_k(const u16* __restrict__ A,
                                                const u16* __restrict__ W,
                                                const float* __restrict__ bias,
                                                const float* __restrict__ res,
                                                const float* __restrict__ g2,
                                                const float* __restrict__ b2,
                                                float* __restrict__ x2,
                                                u16* __restrict__ h2)
{
    constexpr int K = 192;
    __shared__ __align__(16) u16 As[2 * 2048];   // 8 KB  [kt][64 rows][32 k]
    __shared__ __align__(16) u16 Bs[2 * 6144];   // 24 KB [kt][192 rows][32 k]
    const int t = threadIdx.x, bm = blockIdx.x;
    const int lane = t & 63, wv = t >> 6;
    const int r16 = lane & 15, quad = lane >> 4;
    const int ar = t >> 2, ac = (t & 3) * 8;
    const size_t abase = (size_t)bm * 64 * K;

    f32x4 acc[12];
    #pragma unroll
    for (int fn = 0; fn < 12; fn++) acc[fn] = (f32x4){0.f, 0.f, 0.f, 0.f};

    for (int kc = 0; kc < K; kc += 64) {
        if (kc) __syncthreads();   // WAR: prior chunk's ds_reads done
        #pragma unroll
        for (int kt = 0; kt < 2; kt++) {
            gl2lds(&A[abase + (size_t)ar * K + kc + kt * 32 + ac], &As[kt * 2048 + 8 * t]);
            #pragma unroll
            for (int bb = 0; bb < 3; bb++)
                gl2lds(&W[(size_t)(bb * 64 + ar) * K + kc + kt * 32 + ac],
                       &Bs[kt * 6144 + bb * 2048 + 8 * t]);
        }
        __syncthreads();           // drains the 8 async loads
        #pragma unroll
        for (int kt = 0; kt < 2; kt++) {
            s16x8 af = *(const s16x8*)&As[kt * 2048 + (wv * 16 + r16) * 32 + quad * 8];
            #pragma unroll
            for (int fn = 0; fn < 12; fn++) {
                s16x8 bf = *(const s16x8*)&Bs[kt * 6144 + (fn * 16 + r16) * 32 + quad * 8];
                acc[fn] = __builtin_amdgcn_mfma_f32_16x16x32_bf16(af, bf, acc[fn], 0, 0, 0);
            }
        }
    }

    // ---- fused epilogue: window-reverse + residual + LN2, per row ----
    #pragma unroll
    for (int r = 0; r < 4; r++) {
        const int grow = bm * 64 + wv * 16 + quad * 4 + r;
        int win = grow / 343, n = grow - win * 343;
        int bi = win >> 6, wi = win & 63;
        int hw = wi >> 4, ww = (wi >> 2) & 3, tw = wi & 3;
        int ph = n / 49, rem = n - ph * 49;
        int pw = rem / 7, pt = rem - pw * 7;
        int h = hw * 7 + ph + 3; if (h >= 28) h -= 28;
        int w = ww * 7 + pw + 3; if (w >= 28) w -= 28;
        int tt = tw * 7 + pt + 3; if (tt >= 28) tt -= 28;
        int l = (h * 28 + w) * 28 + tt;
        size_t rowbase = ((size_t)bi * L_TOK + l) * C_DIM;

        float y[12];
        float s = 0.f, sq = 0.f;
        #pragma unroll
        for (int fn = 0; fn < 12; fn++) {
            const int gcol = fn * 16 + r16;
            float v = acc[fn][r] + bias[gcol] + res[rowbase + gcol];
            y[fn] = v; s += v; sq += v * v;
        }
        // reduce across the 16 lanes of this quad group (they hold the row)
        #pragma unroll
        for (int off = 1; off < 16; off <<= 1) {
            s += __shfl_xor(s, off, 64);
            sq += __shfl_xor(sq, off, 64);
        }
        const float mean = s * (1.0f / 192.0f);
        float var = sq * (1.0f / 192.0f) - mean * mean;
        var = fmaxf(var, 0.0f);
        const float rstd = rsqrtf(var + 1e-5f);
        #pragma unroll
        for (int fn = 0; fn < 12; fn++) {
            const int gcol = fn * 16 + r16;
            x2[rowbase + gcol] = y[fn];
            h2[rowbase + gcol] = f2bf((y[fn] - mean) * rstd * g2[gcol] + b2[gcol]);
        }
    }
}

// ---------------------------------------------------------------------------
// MFMA attention. Block = (head hh, window win), 4 waves (256 thr).
// LDS 50.7 KB -> 3 blocks/CU (grid 768 = 256 CU x 3, full residency).
// FROZEN at R4-verified state (65-74 us band):
//  - folded 48-slab bf16 bias table (mask-free softmax body).
//  - ones-MFMA rowsum + v_cvt_pk_bf16_f32 P-pack.
//  - BOTH lgkmcnt(0) fences in the PV loop are register-pressure dams:
//    removing them spilled sacc to scratch (R3: +200 MB HBM, 76->125 us).
// ---------------------------------------------------------------------------
__global__ __launch_bounds__(256, 3) void attn_k(const u16* __restrict__ qkv,
                                                 const u16* __restrict__ biasAll,
                                                 u16* __restrict__ out)
{
    __shared__ __align__(16) u16 Ks[352 * 32];       // 22528 B
    __shared__ __align__(16) u16 Vt[32 * 360];       // 23040 B
    __shared__ __align__(16) u16 Pb[4][16 * 40];     //  5120 B

    const int hh = blockIdx.x;   // head 0..5
    const int win = blockIdx.y;  // 0..127
    const int wi = win & 63;
    const int t = threadIdx.x, lane = t & 63, wv = t >> 6;
    const int r16 = lane & 15, quad = lane >> 4;
    const size_t qbase = (size_t)win * 343 * 576 + hh * 32;

    // ---- stage K rows (343 x 32), zero pad rows 343..351 ----
    for (int j = t; j < 343 * 4; j += 256) {
        int m = j >> 2, ch = j & 3;
        *(uint4*)&Ks[m * 32 + ch * 8] = *(const uint4*)&qkv[qbase + (size_t)m * 576 + 192 + ch * 8];
    }
    if (t < 36) {
        int m = 343 + (t >> 2), ch = t & 3;
        *(uint4*)&Ks[m * 32 + ch * 8] = (uint4){0u, 0u, 0u, 0u};
    }
    // ---- stage V transposed + column-permuted: Vt[d][phys(m)] ----
    for (int i = t; i < 343 * 16; i += 256) {
        int m = i >> 4, d2 = (i & 15) * 2;
        int pm = (m & ~31) + 2 * (m & 15) + ((m >> 4) & 1);
        u32 w2 = *(const u32*)&qkv[qbase + (size_t)m * 576 + 384 + d2];
        Vt[d2 * 360 + pm] = (u16)(w2 & 0xffffu);
        Vt[(d2 + 1) * 360 + pm] = (u16)(w2 >> 16);
    }
    // zero pads (logical m 343..351 at their permuted slots), all 32 d rows
    for (int i = t; i < 32 * 9; i += 256) {
        int d = i / 9, m = 343 + i % 9;
        int pm = (m & ~31) + 2 * (m & 15) + ((m >> 4) & 1);
        Vt[d * 360 + pm] = 0;
    }
    __syncthreads();

    // window type -> pre-folded bias+mask slab
    const int wt = (((wi >> 4) == 3) ? 4 : 0) | ((((wi >> 2) & 3) == 3) ? 2 : 0)
                 | (((wi & 3) == 3) ? 1 : 0);
    const u16* biashT = biasAll + (size_t)(hh * 8 + wt) * 352 * BT_STR;

    // ones B-fragment (bf16 1.0 everywhere) for the rowsum MFMA
    s16x8 onesb;
    #pragma unroll
    for (int j = 0; j < 8; j++) onesb[j] = (short)0x3f80;

    for (int qt = 0; qt < 6; qt++) {
        const int row0 = qt * 64 + wv * 16;          // wave's 16 rows
        if (row0 > 342) continue;                    // wave-uniform early out
        // ---- Q A-fragment (row = r16, k = quad*8+j), clamped rows ----
        int qrow = row0 + r16; if (qrow > 342) qrow = 342;
        s16x8 qa = *(const s16x8*)&qkv[qbase + (size_t)qrow * 576 + quad * 8];

        const int n0 = row0 + quad * 4;

        // ---- S = Q K^T, acc init from folded bf16 bias+mask (uint2) ----
        f32x4 sacc[22];
        #pragma unroll
        for (int fn = 0; fn < 22; fn++) {
            const int col = fn * 16 + r16;           // key idx, pads included
            uint2 bv = *(const uint2*)&biashT[(size_t)col * BT_STR + n0];
            sacc[fn][0] = bflo(bv.x);
            sacc[fn][1] = bfhi(bv.x);
            sacc[fn][2] = bflo(bv.y);
            sacc[fn][3] = bfhi(bv.y);
        }
        #pragma unroll
        for (int fn = 0; fn < 22; fn++) {
            s16x8 kb = *(const s16x8*)&Ks[(fn * 16 + r16) * 32 + quad * 8];
            sacc[fn] = __builtin_amdgcn_mfma_f32_16x16x32_bf16(qa, kb, sacc[fn], 0, 0, 0);
        }

        // ---- softmax: p = exp2(s); mask/pad already -inf-folded -> 0 ----
        #pragma unroll
        for (int fn = 0; fn < 22; fn++) {
            #pragma unroll
            for (int r = 0; r < 4; r++)
                sacc[fn][r] = exp2f(fminf(sacc[fn][r], 42.0f));
        }

        // ---- PV in 32-col chunks: packed C->LDS->A round-trip + MFMA ----
        // osum accumulates P @ ones == rowsum (row layout matches n0+r).
        u16* pw = &Pb[wv][0];
        u32* pw32 = (u32*)pw;
        f32x4 oacc0 = (f32x4){0.f, 0.f, 0.f, 0.f};
        f32x4 oacc1 = (f32x4){0.f, 0.f, 0.f, 0.f};
        f32x4 osum  = (f32x4){0.f, 0.f, 0.f, 0.f};
        #pragma unroll
        for (int c = 0; c < 11; c++) {
            // WAR fence: prior chunk's reads complete before overwrite
            // (also a register-pressure dam -- see kernel comment)
            asm volatile("s_waitcnt lgkmcnt(0)" ::: "memory");
            #pragma unroll
            for (int r = 0; r < 4; r++)
                pw32[(quad * 4 + r) * 20 + r16] = cvt_pk_bf16(sacc[2 * c][r], sacc[2 * c + 1][r]);
            // RAW fence: writes committed before reads issue
            asm volatile("s_waitcnt lgkmcnt(0)" ::: "memory");
            s16x8 pa = *(const s16x8*)&pw[r16 * 40 + quad * 8];
            s16x8 vb0 = *(const s16x8*)&Vt[r16 * 360 + c * 32 + quad * 8];
            s16x8 vb1 = *(const s16x8*)&Vt[(16 + r16) * 360 + c * 32 + quad * 8];
            oacc0 = __builtin_amdgcn_mfma_f32_16x16x32_bf16(pa, vb0, oacc0, 0, 0, 0);
            oacc1 = __builtin_amdgcn_mfma_f32_16x16x32_bf16(pa, vb1, oacc1, 0, 0, 0);
            osum  = __builtin_amdgcn_mfma_f32_16x16x32_bf16(pa, onesb, osum, 0, 0, 0);
        }

        // ---- epilogue: fold 1/rowsum, store bf16 ----
        #pragma unroll
        for (int r = 0; r < 4; r++) {
            const int n = n0 + r;
            if (n < 343) {
                const float rs = osum[r];
                const float inv = rs > 0.0f ? 1.0f / rs : 0.0f;
                size_t o = ((size_t)win * 343 + n) * C_DIM + hh * 32;
                out[o + r16] = f2bf(oacc0[r] * inv);
                out[o + 16 + r16] = f2bf(oacc1[r] * inv);
            }
        }
    }
}

// ---------------------------------------------------------------------------
extern "C" void kernel_launch(void* const* d_in, const int* in_sizes, int n_in,
                              void* d_out, int out_size, void* d_ws, size_t ws_size,
                              hipStream_t stream)
{
    const float* x      = (const float*)d_in[0];
    const float* g1     = (const float*)d_in[2];
    const float* b1     = (const float*)d_in[3];
    const float* qkv_w  = (const float*)d_in[4];
    const float* qkv_b  = (const float*)d_in[5];
    const float* rpb    = (const float*)d_in[6];
    const float* proj_w = (const float*)d_in[7];
    const float* proj_b = (const float*)d_in[8];
    const float* g2     = (const float*)d_in[9];
    const float* b2     = (const float*)d_in[10];
    const float* fc1_w  = (const float*)d_in[11];
    const float* fc1_b  = (const float*)d_in[12];
    const float* fc2_w  = (const float*)d_in[13];
    const float* fc2_b  = (const float*)d_in[14];

    // workspace layout (bytes). Region lifetimes (stream-ordered):
    //   [0, 16.9M):    xw (ln1->qkv) -> biasT (bias48->attn) -> h2 (projln->fc1)
    //   [16.9M, 67.4M): qkv (qkv->attn) }  a1 (fc1->fc2) overlays
    //   [67.4M, 84.3M): attn_out (attn->projln) }  both, dead by fc1
    //   [84.3M, 118M):  x2 f32 (projln->fc2 residual)
    //   [118M, ...):    wbf weight cache
    char* ws = (char*)d_ws;
    u16* xw        = (u16*)(ws + 0);                 // 16,861,184 B
    u16* biasT     = (u16*)(ws + 0);                 // 11,894,784 B (after QKV gemm)
    u16* h2        = (u16*)(ws + 0);                 // 16,861,184 B (after attn)
    u16* qkv       = (u16*)(ws + 16861184);          // 50,583,552 B
    u16* a1        = (u16*)(ws + 16861184);          // 67,444,736 B (after projln)
    u16* attn_out  = (u16*)(ws + 67444736);          // 16,861,184 B
    float* x2      = (float*)(ws + 84305920);        // 33,722,368 B
    u16* wbf       = (u16*)(ws + 118028288);         //    884,736 B  (~113 MB total)
    u16* qkv_wb = wbf;
    u16* proj_wb = wbf + 110592;
    u16* fc1_wb = wbf + 147456;
    u16* fc2_wb = wbf + 294912;

    cvt_k<<<dim3(1728), 256, 0, stream>>>(qkv_w, proj_w, fc1_w, fc2_w, wbf);
    ln_k<0><<<dim3(10976), 256, 0, stream>>>(x, g1, b1, xw);
    gemm64_k<192, 0, 9><<<dim3(9 * 686), 256, 0, stream>>>(xw, qkv_wb, qkv_b, qkv, nullptr, 576);
    bias48_k<<<dim3(5808), 256, 0, stream>>>(rpb, biasT);
    attn_k<<<dim3(6, 128), 256, 0, stream>>>(qkv, biasT, attn_out);
    projln_k<<<dim3(686), 256, 0, stream>>>(attn_out, proj_wb, proj_b, x, g2, b2, x2, h2);
    gemm64_k<192, 1, 12><<<dim3(12 * 686), 256, 0, stream>>>(h2, fc1_wb, fc1_b, a1, nullptr, 768);
    gemm64_k<768, 2, 3><<<dim3(3 * 686), 256, 0, stream>>>(a1, fc2_wb, fc2_b, d_out, x2, 192);
}

// Round 11
// 320.052 us; speedup vs baseline: 1.0758x; 1.0047x over previous
//
#include <hip/hip_runtime.h>
#include <hip/hip_bf16.h>

typedef unsigned short u16;
typedef unsigned int u32;
typedef __attribute__((ext_vector_type(8))) short s16x8;
typedef __attribute__((ext_vector_type(4))) float f32x4;

__device__ __forceinline__ u16 f2bf(float f) {
    union { float f; u32 u; } x; x.f = f;
    u32 r = x.u + 0x7fffu + ((x.u >> 16) & 1u);
    return (u16)(r >> 16);
}
// packed-bf16 u32 -> two f32 (lo / hi), 1 VALU op each
__device__ __forceinline__ float bflo(u32 v) {
    union { u32 u; float f; } x; x.u = v << 16; return x.f;
}
__device__ __forceinline__ float bfhi(u32 v) {
    union { u32 u; float f; } x; x.u = v & 0xffff0000u; return x.f;
}
// two f32 -> packed bf16x2 in ONE VALU op (RNE), lo = a, hi = b
__device__ __forceinline__ u32 cvt_pk_bf16(float a, float b) {
    u32 r;
    asm("v_cvt_pk_bf16_f32 %0, %1, %2" : "=v"(r) : "v"(a), "v"(b));
    return r;
}
// async global->LDS, 16B per lane. LDS dest must be wave-uniform base + lane*16
__device__ __forceinline__ void gl2lds(const u16* g, u16* l) {
    __builtin_amdgcn_global_load_lds(
        (const __attribute__((address_space(1))) unsigned int*)g,
        (__attribute__((address_space(3))) unsigned int*)l, 16, 0, 0);
}

#define L_TOK 21952      // 28^3
#define C_DIM 192
#define LOG2E 1.4426950408889634f
#define Q2SCALE 0.2550565444463649f   // (1/sqrt(32)) * log2(e)
#define BT_STR 352       // bias table query-stride (n0+3 <= 351)

// ---------------------------------------------------------------------------
// Convert the 4 weight matrices f32 -> bf16 (contiguous dst buffer).
// ---------------------------------------------------------------------------
__global__ __launch_bounds__(256) void cvt_k(const float* __restrict__ s0, // 110592 qkv_w
                                             const float* __restrict__ s1, // 36864  proj_w
                                             const float* __restrict__ s2, // 147456 fc1_w
                                             const float* __restrict__ s3, // 147456 fc2_w
                                             u16* __restrict__ dst)
{
    int i = blockIdx.x * 256 + threadIdx.x;   // grid covers 442368
    float v;
    if (i < 110592) v = s0[i];
    else if (i < 147456) v = s1[i - 110592];
    else if (i < 294912) v = s2[i - 147456];
    else v = s3[i - 294912];
    dst[i] = f2bf(v);
}

// ---------------------------------------------------------------------------
// Rel-pos bias per (head, window-type), TRANSPOSED (key-major), premultiplied
// by log2(e), structural shift-mask and pad FOLDED IN, stored bf16:
//   biasT[hh*8+wt][key m (352)][query n (352)]  (bf16, 11.9 MB, L3-resident).
// masked (different shift region) -> -100 -> exp2 underflows to 0.
// pad rows/cols (>342)            -> -1e5 -> exp2 == 0 exactly.
// ---------------------------------------------------------------------------
__global__ __launch_bounds__(256) void bias48_k(const float* __restrict__ rpb,
                                                u16* __restrict__ biasT)
{
    const int gid = blockIdx.x * 256 + threadIdx.x;   // < 48*352*88
    const int z = gid / 30976;                        // 352*88
    const int rem = gid - z * 30976;
    const int m = rem / 88;
    const int n0 = (rem - m * 88) * 4;
    const int hh = z >> 3, wt = z & 7;

    u16 v[4];
    if (m <= 342) {
        const int hm = m / 49, r2 = m - hm * 49, wm = r2 / 7, tm = r2 - wm * 7;
        const int rm = ((wt & 4) ? (hm < 4 ? 1 : 2) : 0) * 9
                     + ((wt & 2) ? (wm < 4 ? 1 : 2) : 0) * 3
                     + ((wt & 1) ? (tm < 4 ? 1 : 2) : 0);
        #pragma unroll
        for (int j = 0; j < 4; j++) {
            const int n = n0 + j;
            float b = -100000.0f;
            if (n <= 342) {
                int hq = n / 49, r1 = n - hq * 49, wq = r1 / 7, tq = r1 - wq * 7;
                int idx = ((hq - hm + 6) * 13 + (wq - wm + 6)) * 13 + (tq - tm + 6);
                b = rpb[idx * 6 + hh];
                int rq = ((wt & 4) ? (hq < 4 ? 1 : 2) : 0) * 9
                       + ((wt & 2) ? (wq < 4 ? 1 : 2) : 0) * 3
                       + ((wt & 1) ? (tq < 4 ? 1 : 2) : 0);
                if (rq != rm) b -= 100.0f;
                b *= LOG2E;
            }
            v[j] = f2bf(b);
        }
    } else {
        const u16 neg = f2bf(-100000.0f);
        v[0] = neg; v[1] = neg; v[2] = neg; v[3] = neg;
    }
    u32 lo = (u32)v[0] | ((u32)v[1] << 16);
    u32 hi = (u32)v[2] | ((u32)v[3] << 16);
    *(uint2*)&biasT[((size_t)z * 352 + m) * BT_STR + n0] = (uint2){lo, hi};
}

// ---------------------------------------------------------------------------
// LayerNorm: f32 in, bf16 out. MODE 0 only now: LN + cyclic shift(-3) +
// window partition scatter -> xw (Bn*343, 192).  (LN2 is fused into projln_k.)
// ---------------------------------------------------------------------------
template<int MODE>
__global__ __launch_bounds__(256) void ln_k(const float* __restrict__ in,
                                            const float* __restrict__ g,
                                            const float* __restrict__ b,
                                            u16* __restrict__ out)
{
    const int lane = threadIdx.x & 63, wv = threadIdx.x >> 6;
    const int tok = blockIdx.x * 4 + wv;   // < 43904 always (10976*4)
    size_t base = (size_t)tok * C_DIM;
    float x0 = in[base + lane];
    float x1 = in[base + 64 + lane];
    float x2 = in[base + 128 + lane];
    float s = x0 + x1 + x2;
    float sq = x0 * x0 + x1 * x1 + x2 * x2;
    #pragma unroll
    for (int off = 32; off > 0; off >>= 1) {
        s += __shfl_xor(s, off, 64);
        sq += __shfl_xor(sq, off, 64);
    }
    const float mean = s * (1.0f / 192.0f);
    float var = sq * (1.0f / 192.0f) - mean * mean;
    var = fmaxf(var, 0.0f);
    const float rstd = rsqrtf(var + 1e-5f);

    size_t obase;
    if (MODE == 0) {
        int bi = tok / L_TOK;
        int l = tok - bi * L_TOK;
        int h = l / 784;
        int rm = l - h * 784;
        int w = rm / 28;
        int t = rm - w * 28;
        int hs = h + 25; if (hs >= 28) hs -= 28;
        int ws = w + 25; if (ws >= 28) ws -= 28;
        int ts = t + 25; if (ts >= 28) ts -= 28;
        int win = ((bi * 4 + hs / 7) * 4 + ws / 7) * 4 + ts / 7;
        int n = (hs % 7) * 49 + (ws % 7) * 7 + (ts % 7);
        obase = ((size_t)win * 343 + n) * C_DIM;
    } else {
        obase = base;
    }
    #pragma unroll
    for (int i = 0; i < 3; i++) {
        int c = lane + i * 64;
        float xv = (i == 0) ? x0 : (i == 1) ? x1 : x2;
        float y = (xv - mean) * rstd * g[c] + b[c];
        out[obase + c] = f2bf(y);
    }
}

// ---------------------------------------------------------------------------
// 64x64-tile bf16 MFMA GEMM (qkv / fc1 / fc2): C = A @ W^T + bias.
// R11: T3+T4 pipelined K-loop. Double-buffered LDS (32 KB -> 5 blocks/CU),
// STAGE(c+1) issued BEFORE compute(c), then **counted** s_waitcnt vmcnt(4)
// (chunk c's 4 loads landed; c+1's stay in flight) + RAW s_barrier -- never
// vmcnt(0) in the loop. Per-wave vmcnt at the barrier collectively
// guarantees all waves' chunk-c loads landed. The old __syncthreads drained
// the queue every chunk (the 2.5x issue-bound gap R4-R10 never closed).
// sched_barrier(0) after the barrier stops ds_read hoisting (rule 18).
// R10's bijective XCD-chunk swizzle retained.
// EPI: 0 = bias, q-cols (gcol<192) pre-scaled -> bf16 (QKV)
//      1 = bias + exact GELU -> bf16 (fc1)
//      2 = bias + f32 residual -> f32 out (fc2 -> d_out)
// ---------------------------------------------------------------------------
template<int K, int EPI, int NX>
__global__ __launch_bounds__(256, 8) void gemm64_k(const u16* __restrict__ A,
                                                   const u16* __restrict__ W,
                                                   const float* __restrict__ bias,
                                                   void* __restrict__ outp,
                                                   const void* __restrict__ resp,
                                                   int Ncols)
{
    constexpr int NC = K / 64;
    __shared__ __align__(16) u16 As[2][4096];    // 2 x 8 KB: [buf][kt][64r][32k]
    __shared__ __align__(16) u16 Bs[2][4096];    // 2 x 8 KB
    const int t = threadIdx.x;
    // --- bijective XCD-chunk swizzle (HW round-robins orig%8 -> XCD) ---
    constexpr int NWG = NX * 686;
    constexpr int QQ = NWG >> 3, RR = NWG & 7;
    const int orig = blockIdx.x;
    const int xcd = orig & 7, rnk = orig >> 3;
    const int wgid = (xcd < RR ? xcd * (QQ + 1) : RR * (QQ + 1) + (xcd - RR) * QQ) + rnk;
    const int bm = wgid / NX;
    const int n0 = (wgid - bm * NX) * 64;

    const int lane = t & 63, wv = t >> 6;
    const int r16 = lane & 15, quad = lane >> 4;
    const int ar = t >> 2, ac = (t & 3) * 8;     // 4 threads/row, 8 u16 each
    const size_t abase = (size_t)bm * 64 * K;

    f32x4 acc[4];
    #pragma unroll
    for (int fn = 0; fn < 4; fn++) acc[fn] = (f32x4){0.f, 0.f, 0.f, 0.f};

    auto STAGE = [&](int c, int b) {
        #pragma unroll
        for (int kt = 0; kt < 2; kt++) {
            gl2lds(&A[abase + (size_t)ar * K + c * 64 + kt * 32 + ac], &As[b][kt * 2048 + 8 * t]);
            gl2lds(&W[(size_t)(n0 + ar) * K + c * 64 + kt * 32 + ac], &Bs[b][kt * 2048 + 8 * t]);
        }
    };

    STAGE(0, 0);
    for (int c = 0; c < NC; ++c) {
        const int cur = c & 1;
        if (c + 1 < NC) {
            STAGE(c + 1, cur ^ 1);   // prefetch stays in flight across barrier
            asm volatile("s_waitcnt vmcnt(4)" ::: "memory");
        } else {
            asm volatile("s_waitcnt vmcnt(0)" ::: "memory");
        }
        __builtin_amdgcn_s_barrier();
        __builtin_amdgcn_sched_barrier(0);
        #pragma unroll
        for (int kt = 0; kt < 2; kt++) {
            s16x8 af = *(const s16x8*)&As[cur][kt * 2048 + (wv * 16 + r16) * 32 + quad * 8];
            #pragma unroll
            for (int fn = 0; fn < 4; fn++) {
                s16x8 bf = *(const s16x8*)&Bs[cur][kt * 2048 + (fn * 16 + r16) * 32 + quad * 8];
                acc[fn] = __builtin_amdgcn_mfma_f32_16x16x32_bf16(af, bf, acc[fn], 0, 0, 0);
            }
        }
        // WAR: all waves' ds_reads of buf cur are consumed by the MFMAs above
        // (compiler lgkmcnt), so a plain barrier suffices before overwrite.
        __builtin_amdgcn_s_barrier();
    }

    // ---- epilogue: 4 rows x 4 col-fragments per thread ----
    #pragma unroll
    for (int r = 0; r < 4; r++) {
        const int grow = bm * 64 + wv * 16 + quad * 4 + r;
        size_t rowbase = (size_t)grow * ((EPI == 2) ? C_DIM : Ncols);
        #pragma unroll
        for (int fn = 0; fn < 4; fn++) {
            const int gcol = n0 + fn * 16 + r16;
            float v = acc[fn][r] + bias[gcol];
            if (EPI == 0) {
                if (gcol < 192) v *= Q2SCALE;   // pre-scale q (incl. log2e)
                ((u16*)outp)[rowbase + gcol] = f2bf(v);
            } else if (EPI == 1) {
                v = 0.5f * v * (1.0f + erff(v * 0.70710678118654752f));
                ((u16*)outp)[rowbase + gcol] = f2bf(v);
            } else {
                size_t o = rowbase + gcol;
                ((float*)outp)[o] = v + ((const float*)resp)[o];
            }
        }
    }
}

// ---------------------------------------------------------------------------
// FUSED proj GEMM + window-reverse/unshift + residual + LayerNorm2.
// Same T3+T4 pipelined K-loop (vmcnt(8): 8 loads/chunk). LDS 64 KB ->
// 2 blocks/CU (grid 686 = 2.7 blocks/CU anyway). Tile 64 rows x ALL 192
// cols; row LN via quad-group shuffle reduce; emits x2 (f32) + h2 (bf16).
// ---------------------------------------------------------------------------
__global__ __launch_bounds__(256) void projln_k(const u16* __restrict__ A,
                                                const u16* __restrict__ W,
                                                const float* __restrict__ bias,
                                                const float* __restrict__ res,
                                                const float* __restrict__ g2,
                                                const float* __restrict__ b2,
                                                float* __restrict__ x2,
                                                u16* __restrict__ h2)
{
    constexpr int K = 192, NC = 3;
    __shared__ __align__(16) u16 As[2][4096];    // 2 x 8 KB
    __shared__ __align__(16) u16 Bs[2][12288];   // 2 x 24 KB
    const int t = threadIdx.x, bm = blockIdx.x;
    const int lane = t & 63, wv = t >> 6;
    const int r16 = lane & 15, quad = lane >> 4;
    const int ar = t >> 2, ac = (t & 3) * 8;
    const size_t abase = (size_t)bm * 64 * K;

    f32x4 acc[12];
    #pragma unroll
    for (int fn = 0; fn < 12; fn++) acc[fn] = (f32x4){0.f, 0.f, 0.f, 0.f};

    auto STAGE = [&](int c, int b) {
        #pragma unroll
        for (int kt = 0; kt < 2; kt++) {
            gl2lds(&A[abase + (size_t)ar * K + c * 64 + kt * 32 + ac], &As[b][kt * 2048 + 8 * t]);
            #pragma unroll
            for (int bb = 0; bb < 3; bb++)
                gl2lds(&W[(size_t)(bb * 64 + ar) * K + c * 64 + kt * 32 + ac],
                       &Bs[b][kt * 6144 + bb * 2048 + 8 * t]);
        }
    };

    STAGE(0, 0);
    for (int c = 0; c < NC; ++c) {
        const int cur = c & 1;
        if (c + 1 < NC) {
            STAGE(c + 1, cur ^ 1);
            asm volatile("s_waitcnt vmcnt(8)" ::: "memory");
        } else {
            asm volatile("s_waitcnt vmcnt(0)" ::: "memory");
        }
        __builtin_amdgcn_s_barrier();
        __builtin_amdgcn_sched_barrier(0);
        #pragma unroll
        for (int kt = 0; kt < 2; kt++) {
            s16x8 af = *(const s16x8*)&As[cur][kt * 2048 + (wv * 16 + r16) * 32 + quad * 8];
            #pragma unroll
            for (int fn = 0; fn < 12; fn++) {
                s16x8 bf = *(const s16x8*)&Bs[cur][kt * 6144 + (fn * 16 + r16) * 32 + quad * 8];
                acc[fn] = __builtin_amdgcn_mfma_f32_16x16x32_bf16(af, bf, acc[fn], 0, 0, 0);
            }
        }
        __builtin_amdgcn_s_barrier();
    }

    // ---- fused epilogue: window-reverse + residual + LN2, per row ----
    #pragma unroll
    for (int r = 0; r < 4; r++) {
        const int grow = bm * 64 + wv * 16 + quad * 4 + r;
        int win = grow / 343, n = grow - win * 343;
        int bi = win >> 6, wi = win & 63;
        int hw = wi >> 4, ww = (wi >> 2) & 3, tw = wi & 3;
        int ph = n / 49, rem = n - ph * 49;
        int pw = rem / 7, pt = rem - pw * 7;
        int h = hw * 7 + ph + 3; if (h >= 28) h -= 28;
        int w = ww * 7 + pw + 3; if (w >= 28) w -= 28;
        int tt = tw * 7 + pt + 3; if (tt >= 28) tt -= 28;
        int l = (h * 28 + w) * 28 + tt;
        size_t rowbase = ((size_t)bi * L_TOK + l) * C_DIM;

        float y[12];
        float s = 0.f, sq = 0.f;
        #pragma unroll
        for (int fn = 0; fn < 12; fn++) {
            const int gcol = fn * 16 + r16;
            float v = acc[fn][r] + bias[gcol] + res[rowbase + gcol];
            y[fn] = v; s += v; sq += v * v;
        }
        // reduce across the 16 lanes of this quad group (they hold the row)
        #pragma unroll
        for (int off = 1; off < 16; off <<= 1) {
            s += __shfl_xor(s, off, 64);
            sq += __shfl_xor(sq, off, 64);
        }
        const float mean = s * (1.0f / 192.0f);
        float var = sq * (1.0f / 192.0f) - mean * mean;
        var = fmaxf(var, 0.0f);
        const float rstd = rsqrtf(var + 1e-5f);
        #pragma unroll
        for (int fn = 0; fn < 12; fn++) {
            const int gcol = fn * 16 + r16;
            x2[rowbase + gcol] = y[fn];
            h2[rowbase + gcol] = f2bf((y[fn] - mean) * rstd * g2[gcol] + b2[gcol]);
        }
    }
}

// ---------------------------------------------------------------------------
// MFMA attention. Block = (head hh, window win), 4 waves (256 thr).
// LDS 50.7 KB -> 3 blocks/CU (grid 768 = 256 CU x 3, full residency).
// FROZEN at R4-verified state (65-74 us band):
//  - folded 48-slab bf16 bias table (mask-free softmax body).
//  - ones-MFMA rowsum + v_cvt_pk_bf16_f32 P-pack.
//  - BOTH lgkmcnt(0) fences in the PV loop are register-pressure dams:
//    removing them spilled sacc to scratch (R3: +200 MB HBM, 76->125 us).
// ---------------------------------------------------------------------------
__global__ __launch_bounds__(256, 3) void attn_k(const u16* __restrict__ qkv,
                                                 const u16* __restrict__ biasAll,
                                                 u16* __restrict__ out)
{
    __shared__ __align__(16) u16 Ks[352 * 32];       // 22528 B
    __shared__ __align__(16) u16 Vt[32 * 360];       // 23040 B
    __shared__ __align__(16) u16 Pb[4][16 * 40];     //  5120 B

    const int hh = blockIdx.x;   // head 0..5
    const int win = blockIdx.y;  // 0..127
    const int wi = win & 63;
    const int t = threadIdx.x, lane = t & 63, wv = t >> 6;
    const int r16 = lane & 15, quad = lane >> 4;
    const size_t qbase = (size_t)win * 343 * 576 + hh * 32;

    // ---- stage K rows (343 x 32), zero pad rows 343..351 ----
    for (int j = t; j < 343 * 4; j += 256) {
        int m = j >> 2, ch = j & 3;
        *(uint4*)&Ks[m * 32 + ch * 8] = *(const uint4*)&qkv[qbase + (size_t)m * 576 + 192 + ch * 8];
    }
    if (t < 36) {
        int m = 343 + (t >> 2), ch = t & 3;
        *(uint4*)&Ks[m * 32 + ch * 8] = (uint4){0u, 0u, 0u, 0u};
    }
    // ---- stage V transposed + column-permuted: Vt[d][phys(m)] ----
    for (int i = t; i < 343 * 16; i += 256) {
        int m = i >> 4, d2 = (i & 15) * 2;
        int pm = (m & ~31) + 2 * (m & 15) + ((m >> 4) & 1);
        u32 w2 = *(const u32*)&qkv[qbase + (size_t)m * 576 + 384 + d2];
        Vt[d2 * 360 + pm] = (u16)(w2 & 0xffffu);
        Vt[(d2 + 1) * 360 + pm] = (u16)(w2 >> 16);
    }
    // zero pads (logical m 343..351 at their permuted slots), all 32 d rows
    for (int i = t; i < 32 * 9; i += 256) {
        int d = i / 9, m = 343 + i % 9;
        int pm = (m & ~31) + 2 * (m & 15) + ((m >> 4) & 1);
        Vt[d * 360 + pm] = 0;
    }
    __syncthreads();

    // window type -> pre-folded bias+mask slab
    const int wt = (((wi >> 4) == 3) ? 4 : 0) | ((((wi >> 2) & 3) == 3) ? 2 : 0)
                 | (((wi & 3) == 3) ? 1 : 0);
    const u16* biashT = biasAll + (size_t)(hh * 8 + wt) * 352 * BT_STR;

    // ones B-fragment (bf16 1.0 everywhere) for the rowsum MFMA
    s16x8 onesb;
    #pragma unroll
    for (int j = 0; j < 8; j++) onesb[j] = (short)0x3f80;

    for (int qt = 0; qt < 6; qt++) {
        const int row0 = qt * 64 + wv * 16;          // wave's 16 rows
        if (row0 > 342) continue;                    // wave-uniform early out
        // ---- Q A-fragment (row = r16, k = quad*8+j), clamped rows ----
        int qrow = row0 + r16; if (qrow > 342) qrow = 342;
        s16x8 qa = *(const s16x8*)&qkv[qbase + (size_t)qrow * 576 + quad * 8];

        const int n0 = row0 + quad * 4;

        // ---- S = Q K^T, acc init from folded bf16 bias+mask (uint2) ----
        f32x4 sacc[22];
        #pragma unroll
        for (int fn = 0; fn < 22; fn++) {
            const int col = fn * 16 + r16;           // key idx, pads included
            uint2 bv = *(const uint2*)&biashT[(size_t)col * BT_STR + n0];
            sacc[fn][0] = bflo(bv.x);
            sacc[fn][1] = bfhi(bv.x);
            sacc[fn][2] = bflo(bv.y);
            sacc[fn][3] = bfhi(bv.y);
        }
        #pragma unroll
        for (int fn = 0; fn < 22; fn++) {
            s16x8 kb = *(const s16x8*)&Ks[(fn * 16 + r16) * 32 + quad * 8];
            sacc[fn] = __builtin_amdgcn_mfma_f32_16x16x32_bf16(qa, kb, sacc[fn], 0, 0, 0);
        }

        // ---- softmax: p = exp2(s); mask/pad already -inf-folded -> 0 ----
        #pragma unroll
        for (int fn = 0; fn < 22; fn++) {
            #pragma unroll
            for (int r = 0; r < 4; r++)
                sacc[fn][r] = exp2f(fminf(sacc[fn][r], 42.0f));
        }

        // ---- PV in 32-col chunks: packed C->LDS->A round-trip + MFMA ----
        // osum accumulates P @ ones == rowsum (row layout matches n0+r).
        u16* pw = &Pb[wv][0];
        u32* pw32 = (u32*)pw;
        f32x4 oacc0 = (f32x4){0.f, 0.f, 0.f, 0.f};
        f32x4 oacc1 = (f32x4){0.f, 0.f, 0.f, 0.f};
        f32x4 osum  = (f32x4){0.f, 0.f, 0.f, 0.f};
        #pragma unroll
        for (int c = 0; c < 11; c++) {
            // WAR fence: prior chunk's reads complete before overwrite
            // (also a register-pressure dam -- see kernel comment)
            asm volatile("s_waitcnt lgkmcnt(0)" ::: "memory");
            #pragma unroll
            for (int r = 0; r < 4; r++)
                pw32[(quad * 4 + r) * 20 + r16] = cvt_pk_bf16(sacc[2 * c][r], sacc[2 * c + 1][r]);
            // RAW fence: writes committed before reads issue
            asm volatile("s_waitcnt lgkmcnt(0)" ::: "memory");
            s16x8 pa = *(const s16x8*)&pw[r16 * 40 + quad * 8];
            s16x8 vb0 = *(const s16x8*)&Vt[r16 * 360 + c * 32 + quad * 8];
            s16x8 vb1 = *(const s16x8*)&Vt[(16 + r16) * 360 + c * 32 + quad * 8];
            oacc0 = __builtin_amdgcn_mfma_f32_16x16x32_bf16(pa, vb0, oacc0, 0, 0, 0);
            oacc1 = __builtin_amdgcn_mfma_f32_16x16x32_bf16(pa, vb1, oacc1, 0, 0, 0);
            osum  = __builtin_amdgcn_mfma_f32_16x16x32_bf16(pa, onesb, osum, 0, 0, 0);
        }

        // ---- epilogue: fold 1/rowsum, store bf16 ----
        #pragma unroll
        for (int r = 0; r < 4; r++) {
            const int n = n0 + r;
            if (n < 343) {
                const float rs = osum[r];
                const float inv = rs > 0.0f ? 1.0f / rs : 0.0f;
                size_t o = ((size_t)win * 343 + n) * C_DIM + hh * 32;
                out[o + r16] = f2bf(oacc0[r] * inv);
                out[o + 16 + r16] = f2bf(oacc1[r] * inv);
            }
        }
    }
}

// ---------------------------------------------------------------------------
extern "C" void kernel_launch(void* const* d_in, const int* in_sizes, int n_in,
                              void* d_out, int out_size, void* d_ws, size_t ws_size,
                              hipStream_t stream)
{
    const float* x      = (const float*)d_in[0];
    const float* g1     = (const float*)d_in[2];
    const float* b1     = (const float*)d_in[3];
    const float* qkv_w  = (const float*)d_in[4];
    const float* qkv_b  = (const float*)d_in[5];
    const float* rpb    = (const float*)d_in[6];
    const float* proj_w = (const float*)d_in[7];
    const float* proj_b = (const float*)d_in[8];
    const float* g2     = (const float*)d_in[9];
    const float* b2     = (const float*)d_in[10];
    const float* fc1_w  = (const float*)d_in[11];
    const float* fc1_b  = (const float*)d_in[12];
    const float* fc2_w  = (const float*)d_in[13];
    const float* fc2_b  = (const float*)d_in[14];

    // workspace layout (bytes). Region lifetimes (stream-ordered):
    //   [0, 16.9M):    xw (ln1->qkv) -> biasT (bias48->attn) -> h2 (projln->fc1)
    //   [16.9M, 67.4M): qkv (qkv->attn) }  a1 (fc1->fc2) overlays
    //   [67.4M, 84.3M): attn_out (attn->projln) }  both, dead by fc1
    //   [84.3M, 118M):  x2 f32 (projln->fc2 residual)
    //   [118M, ...):    wbf weight cache
    char* ws = (char*)d_ws;
    u16* xw        = (u16*)(ws + 0);                 // 16,861,184 B
    u16* biasT     = (u16*)(ws + 0);                 // 11,894,784 B (after QKV gemm)
    u16* h2        = (u16*)(ws + 0);                 // 16,861,184 B (after attn)
    u16* qkv       = (u16*)(ws + 16861184);          // 50,583,552 B
    u16* a1        = (u16*)(ws + 16861184);          // 67,444,736 B (after projln)
    u16* attn_out  = (u16*)(ws + 67444736);          // 16,861,184 B
    float* x2      = (float*)(ws + 84305920);        // 33,722,368 B
    u16* wbf       = (u16*)(ws + 118028288);         //    884,736 B  (~113 MB total)
    u16* qkv_wb = wbf;
    u16* proj_wb = wbf + 110592;
    u16* fc1_wb = wbf + 147456;
    u16* fc2_wb = wbf + 294912;

    cvt_k<<<dim3(1728), 256, 0, stream>>>(qkv_w, proj_w, fc1_w, fc2_w, wbf);
    ln_k<0><<<dim3(10976), 256, 0, stream>>>(x, g1, b1, xw);
    gemm64_k<192, 0, 9><<<dim3(9 * 686), 256, 0, stream>>>(xw, qkv_wb, qkv_b, qkv, nullptr, 576);
    bias48_k<<<dim3(5808), 256, 0, stream>>>(rpb, biasT);
    attn_k<<<dim3(6, 128), 256, 0, stream>>>(qkv, biasT, attn_out);
    projln_k<<<dim3(686), 256, 0, stream>>>(attn_out, proj_wb, proj_b, x, g2, b2, x2, h2);
    gemm64_k<192, 1, 12><<<dim3(12 * 686), 256, 0, stream>>>(h2, fc1_wb, fc1_b, a1, nullptr, 768);
    gemm64_k<768, 2, 3><<<dim3(3 * 686), 256, 0, stream>>>(a1, fc2_wb, fc2_b, d_out, x2, 192);
}